// Round 5
// baseline (152.432 us; speedup 1.0000x reference)
//
#include <hip/hip_runtime.h>
#include <math.h>

// Problem constants (match reference).
#define T_TOTAL 131072
#define FEAT    8
#define HIDDEN  256
#define MAXK    10
#define BUF     50
#define BT      256   // timesteps per block (4 waves, each fully autonomous)

// Native clang vector type: __builtin_nontemporal_store requires a real
// vector-of-float, not HIP's float4 struct.
typedef float floatx4 __attribute__((ext_vector_type(4)));

__device__ __forceinline__ float fit_loglog(const float Lk[MAXK]) {
    // log(1..10) as float32 constants (natural log, matches jnp.log).
    const float logk[MAXK] = {0.0f,        0.6931472f, 1.0986123f, 1.3862944f,
                              1.6094379f,  1.7917595f, 1.9459101f, 2.0794415f,
                              2.1972246f,  2.3025851f};
    float c = 0.f, sx = 0.f, sy = 0.f, sxy = 0.f, sxx = 0.f;
#pragma unroll
    for (int i = 0; i < MAXK; ++i) {
        if (Lk[i] > 0.0f) {
            const float lx = logk[i];
            const float ly = logf(Lk[i]);
            c   += 1.0f;
            sx  += lx;
            sy  += ly;
            sxy += ly * lx;
            sxx += lx * lx;
        }
    }
    float denom = c * sxx - sx * sx;
    denom = (denom != 0.0f) ? denom : 1.0f;
    const float slope = (c * sxy - sx * sy) / denom;
    return (c > 1.0f) ? -slope : 0.0f;
}

__global__ __launch_bounds__(BT) void hfd_fused(const float* __restrict__ x,
                                                const float* __restrict__ w_lin,
                                                const float* __restrict__ b_lin,
                                                floatx4* __restrict__ outv) {
    // Per-wave private staging segments: 113 prices each (64 + 49 history),
    // padded to 128. NO __syncthreads in this kernel — each wave writes and
    // reads only its own segment; within-wave ds ordering is enforced by the
    // compiler's lgkmcnt waits.
    __shared__ float sp[BT / 64][128];

    const int tid   = threadIdx.x;
    const int lane  = tid & 63;
    const int wid   = tid >> 6;                      // wave id within block
    const int wbase = blockIdx.x * BT + (wid << 6);  // first timestep of this wave
    float* wsp = sp[wid];

    // Stage this wave's window range: prices p[wbase-49 .. wbase+63].
    {
        const int gt0 = wbase - (BUF - 1) + lane;
        wsp[lane] = (gt0 >= 0) ? x[(size_t)gt0 * FEAT + 3] : 0.0f;
        if (lane < 49) {
            const int gt1 = gt0 + 64;
            wsp[64 + lane] = (gt1 >= 0) ? x[(size_t)gt1 * FEAT + 3] : 0.0f;
        }
    }
    // (compiler inserts s_waitcnt lgkmcnt before the dependent ds_reads below)

    const int t = wbase + lane;
    float hfd = 0.0f;

    if (t >= BUF - 1) {
        // -------- full window: nm1 = 49, compile-time constant --------
        // W[q] = p[t-49+q] = wsp[lane + q]
        float w[BUF];
#pragma unroll
        for (int q = 0; q < BUF; ++q) w[q] = wsp[lane + q];

        float Lk[MAXK];
#pragma unroll
        for (int k = 1; k <= MAXK; ++k) {
            float acc = 0.0f;
#pragma unroll
            for (int m = 0; m < k; ++m) {
                float S = 0.0f;
#pragma unroll
                for (int q = m; q + k <= BUF - 1; q += k)
                    S += fabsf(w[q + k] - w[q]);
                const int len = (BUF - 1 - m) / k + 1;   // always >= 2 here
                acc += S * ((float)(BUF - 1) / (float)(len * k));  // constant folds
            }
            Lk[k - 1] = acc / (float)k;
        }
        hfd = fit_loglog(Lk);
    } else if (t >= MAXK) {
        // -------- partial window: t in [10,48] (block 0, wave 0 only) --------
        const int   nm1  = t;
        const float nm1f = (float)nm1;
        const float* wp  = &wsp[BUF - 1];   // wbase == 0 here; W[q] = p[q]

        float Lk[MAXK];
        for (int k = 1; k <= MAXK; ++k) {
            float acc = 0.0f;
            for (int m = 0; m < k; ++m) {
                float S = 0.0f;
                for (int q = m; q + k <= nm1; q += k)
                    S += fabsf(wp[q + k] - wp[q]);
                const int length = (nm1 >= m) ? ((nm1 - m) / k + 1) : 0;
                if (length >= 2)
                    acc += S * nm1f / (float)(length * k);
            }
            Lk[k - 1] = acc / (float)k;
        }
        hfd = fit_loglog(Lk);
    }
    // t < 10: hfd stays 0 (reference zeroes where n < MAX_K+1).

    // -------- wave-local epilogue: no barrier, no LDS --------
    // Row r's hfd broadcast from lane r via __shfl; lane = which float4 of
    // the 256 hidden units -> 64 lanes x 16 B = one contiguous 1 KB row.
    // Output is never re-read: nontemporal stores reduce cache writeback
    // pressure on the 128 MiB stream.
    const floatx4 wv = ((const floatx4*)w_lin)[lane];
    const floatx4 bv = ((const floatx4*)b_lin)[lane];

#pragma unroll 16
    for (int r = 0; r < 64; ++r) {
        const float h = __shfl(hfd, r, 64);
        floatx4 o;
        o.x = fmaxf(fmaf(h, wv.x, bv.x), 0.0f);
        o.y = fmaxf(fmaf(h, wv.y, bv.y), 0.0f);
        o.z = fmaxf(fmaf(h, wv.z, bv.z), 0.0f);
        o.w = fmaxf(fmaf(h, wv.w, bv.w), 0.0f);
        __builtin_nontemporal_store(o, &outv[(size_t)(wbase + r) * (HIDDEN / 4) + lane]);
    }
}

extern "C" void kernel_launch(void* const* d_in, const int* in_sizes, int n_in,
                              void* d_out, int out_size, void* d_ws, size_t ws_size,
                              hipStream_t stream) {
    const float* x     = (const float*)d_in[0];
    const float* w_lin = (const float*)d_in[1];   // [HIDDEN,1] -> flat 256
    const float* b_lin = (const float*)d_in[2];   // [HIDDEN]
    floatx4* outv = (floatx4*)d_out;

    hfd_fused<<<dim3(T_TOTAL / BT), dim3(BT), 0, stream>>>(x, w_lin, b_lin, outv);
}

// Round 6
// 147.225 us; speedup vs baseline: 1.0354x; 1.0354x over previous
//
#include <hip/hip_runtime.h>
#include <math.h>

// Problem constants (match reference).
#define T_TOTAL 131072
#define FEAT    8
#define HIDDEN  256
#define MAXK    10
#define BUF     50
#define BT      256   // timesteps per block (4 waves, each fully autonomous)

__device__ __forceinline__ float fit_loglog(const float Lk[MAXK]) {
    // log(1..10) as float32 constants (natural log, matches jnp.log).
    const float logk[MAXK] = {0.0f,        0.6931472f, 1.0986123f, 1.3862944f,
                              1.6094379f,  1.7917595f, 1.9459101f, 2.0794415f,
                              2.1972246f,  2.3025851f};
    float c = 0.f, sx = 0.f, sy = 0.f, sxy = 0.f, sxx = 0.f;
#pragma unroll
    for (int i = 0; i < MAXK; ++i) {
        if (Lk[i] > 0.0f) {
            const float lx = logk[i];
            const float ly = logf(Lk[i]);
            c   += 1.0f;
            sx  += lx;
            sy  += ly;
            sxy += ly * lx;
            sxx += lx * lx;
        }
    }
    float denom = c * sxx - sx * sx;
    denom = (denom != 0.0f) ? denom : 1.0f;
    const float slope = (c * sxy - sx * sy) / denom;
    return (c > 1.0f) ? -slope : 0.0f;
}

__global__ __launch_bounds__(BT) void hfd_fused(const float* __restrict__ x,
                                                const float* __restrict__ w_lin,
                                                const float* __restrict__ b_lin,
                                                float4* __restrict__ outv) {
    // Per-wave private staging segments: 113 prices each (64 + 49 history),
    // padded to 128. NO __syncthreads in this kernel — each wave writes and
    // reads only its own segment; within-wave ds ordering is enforced by the
    // compiler's lgkmcnt waits.
    __shared__ float sp[BT / 64][128];

    const int tid   = threadIdx.x;
    const int lane  = tid & 63;
    const int wid   = tid >> 6;                      // wave id within block
    const int wbase = blockIdx.x * BT + (wid << 6);  // first timestep of this wave
    float* wsp = sp[wid];

    // Stage this wave's window range: prices p[wbase-49 .. wbase+63].
    {
        const int gt0 = wbase - (BUF - 1) + lane;
        wsp[lane] = (gt0 >= 0) ? x[(size_t)gt0 * FEAT + 3] : 0.0f;
        if (lane < 49) {
            const int gt1 = gt0 + 64;
            wsp[64 + lane] = (gt1 >= 0) ? x[(size_t)gt1 * FEAT + 3] : 0.0f;
        }
    }
    // (compiler inserts s_waitcnt lgkmcnt before the dependent ds_reads below)

    const int t = wbase + lane;
    float hfd = 0.0f;

    if (t >= BUF - 1) {
        // -------- full window: nm1 = 49, compile-time constant --------
        // W[q] = p[t-49+q] = wsp[lane + q]
        float w[BUF];
#pragma unroll
        for (int q = 0; q < BUF; ++q) w[q] = wsp[lane + q];

        float Lk[MAXK];
#pragma unroll
        for (int k = 1; k <= MAXK; ++k) {
            float acc = 0.0f;
#pragma unroll
            for (int m = 0; m < k; ++m) {
                float S = 0.0f;
#pragma unroll
                for (int q = m; q + k <= BUF - 1; q += k)
                    S += fabsf(w[q + k] - w[q]);
                const int len = (BUF - 1 - m) / k + 1;   // always >= 2 here
                acc += S * ((float)(BUF - 1) / (float)(len * k));  // constant folds
            }
            Lk[k - 1] = acc / (float)k;
        }
        hfd = fit_loglog(Lk);
    } else if (t >= MAXK) {
        // -------- partial window: t in [10,48] (block 0, wave 0 only) --------
        const int   nm1  = t;
        const float nm1f = (float)nm1;
        const float* wp  = &wsp[BUF - 1];   // wbase == 0 here; W[q] = p[q]

        float Lk[MAXK];
        for (int k = 1; k <= MAXK; ++k) {
            float acc = 0.0f;
            for (int m = 0; m < k; ++m) {
                float S = 0.0f;
                for (int q = m; q + k <= nm1; q += k)
                    S += fabsf(wp[q + k] - wp[q]);
                const int length = (nm1 >= m) ? ((nm1 - m) / k + 1) : 0;
                if (length >= 2)
                    acc += S * nm1f / (float)(length * k);
            }
            Lk[k - 1] = acc / (float)k;
        }
        hfd = fit_loglog(Lk);
    }
    // t < 10: hfd stays 0 (reference zeroes where n < MAX_K+1).

    // -------- wave-local epilogue: no barrier, no LDS --------
    // Row r's hfd broadcast from lane r via __shfl; lane = which float4 of
    // the 256 hidden units -> 64 lanes x 16 B = one contiguous 1 KB row.
    // Plain (cached) stores: the 128 MiB output fits in the 256 MiB L3, so
    // dirty lines can drain to HBM lazily AFTER the kernel retires —
    // nontemporal stores forced the drain inside kernel wall-clock (R5).
    const float4 wv = ((const float4*)w_lin)[lane];
    const float4 bv = ((const float4*)b_lin)[lane];

#pragma unroll 16
    for (int r = 0; r < 64; ++r) {
        const float h = __shfl(hfd, r, 64);
        float4 o;
        o.x = fmaxf(fmaf(h, wv.x, bv.x), 0.0f);
        o.y = fmaxf(fmaf(h, wv.y, bv.y), 0.0f);
        o.z = fmaxf(fmaf(h, wv.z, bv.z), 0.0f);
        o.w = fmaxf(fmaf(h, wv.w, bv.w), 0.0f);
        outv[(size_t)(wbase + r) * (HIDDEN / 4) + lane] = o;
    }
}

extern "C" void kernel_launch(void* const* d_in, const int* in_sizes, int n_in,
                              void* d_out, int out_size, void* d_ws, size_t ws_size,
                              hipStream_t stream) {
    const float* x     = (const float*)d_in[0];
    const float* w_lin = (const float*)d_in[1];   // [HIDDEN,1] -> flat 256
    const float* b_lin = (const float*)d_in[2];   // [HIDDEN]
    float4* outv = (float4*)d_out;

    hfd_fused<<<dim3(T_TOTAL / BT), dim3(BT), 0, stream>>>(x, w_lin, b_lin, outv);
}